// Round 4
// baseline (263.521 us; speedup 1.0000x reference)
//
#include <hip/hip_runtime.h>
#include <hip/hip_bf16.h>
#include <math.h>

#define SEQ   2048
#define NHEAD 8

typedef __attribute__((ext_vector_type(8))) short bf16x8;
typedef __attribute__((ext_vector_type(4))) short bf16x4;
typedef __attribute__((ext_vector_type(4))) float f32x4;

static __device__ __forceinline__ short f2bf(float f) {
    __hip_bfloat16 h = __float2bfloat16(f);   // RNE
    return *reinterpret_cast<short*>(&h);
}

// ---------------------------------------------------------------------------
// Weight prep: LDS-tiled 64x64 transpose + bf16 cast (coalesced both sides).
// qg_w[256][512]->wqgT[512][256]; kv_w likewise; o_w[256][256]->owT[256][256].
// grid: 32 + 32 + 16 = 80 blocks.
// ---------------------------------------------------------------------------
__global__ __launch_bounds__(256)
void prep_w_kernel(const float* __restrict__ qg_w, const float* __restrict__ kv_w,
                   const float* __restrict__ o_w, short* __restrict__ wqgT,
                   short* __restrict__ wkvT, short* __restrict__ owT)
{
    __shared__ float t[64][65];
    int bid = blockIdx.x;
    const float* src; short* dst; int N, tr, tc;
    if (bid < 32)      { src = qg_w; dst = wqgT; N = 512; tr = bid >> 3; tc = bid & 7; }
    else if (bid < 64) { bid -= 32; src = kv_w; dst = wkvT; N = 512; tr = bid >> 3; tc = bid & 7; }
    else               { bid -= 64; src = o_w;  dst = owT;  N = 256; tr = bid >> 2; tc = bid & 3; }

    const int tid = threadIdx.x;
    const int rr = tid >> 6;       // 0..3
    const int cc = tid & 63;
#pragma unroll
    for (int s = 0; s < 16; s++)
        t[(s << 2) + rr][cc] =
            src[(size_t)((tr << 6) + (s << 2) + rr) * N + (tc << 6) + cc];
    __syncthreads();
#pragma unroll
    for (int s = 0; s < 16; s++)
        dst[(size_t)((tc << 6) + (s << 2) + rr) * 256 + (tr << 6) + cc]
            = f2bf(t[cc][(s << 2) + rr]);
}

// ---------------------------------------------------------------------------
// QG/KV projection, MFMA; A read as f32 + in-register bf16 cast.
// z=0: QG -> qs(bf16, *scale), gs(f32, sigmoid); z=1: KV -> ks(bf16), vT(bf16).
// Wave tile 16m x 32n over K=256; 4 waves on m. grid (32,16,2).
// ---------------------------------------------------------------------------
__global__ __launch_bounds__(256)
void proj_qgkv_kernel(const float* __restrict__ q_in, const float* __restrict__ kv_in,
                      const short* __restrict__ wqgT, const short* __restrict__ wkvT,
                      const float* __restrict__ qg_b, const float* __restrict__ kv_b,
                      short* __restrict__ qs, float* __restrict__ gs,
                      short* __restrict__ ks, short* __restrict__ vT)
{
    const int z = blockIdx.z;
    const float* __restrict__ A  = z ? kv_in : q_in;
    const short* __restrict__ W  = z ? wkvT : wqgT;
    const float* __restrict__ bv = z ? kv_b : qg_b;

    const int tid = threadIdx.x;
    const int wq = tid >> 6, lane = tid & 63;
    const int ln = lane & 15, quad = lane >> 4;
    const int m0 = blockIdx.x << 6;
    const int n0 = blockIdx.y << 5;

    f32x4 acc[2];
#pragma unroll
    for (int nt = 0; nt < 2; nt++) {
        const float b = bv[n0 + (nt << 4) + ln];
        acc[nt] = (f32x4){b, b, b, b};
    }

    const float* ap = A + (size_t)(m0 + (wq << 4) + ln) * 256 + (quad << 3);
    for (int k8 = 0; k8 < 8; k8++) {
        float4 a0 = *(const float4*)(ap + (k8 << 5));
        float4 a1 = *(const float4*)(ap + (k8 << 5) + 4);
        bf16x8 a;
        a[0] = f2bf(a0.x); a[1] = f2bf(a0.y); a[2] = f2bf(a0.z); a[3] = f2bf(a0.w);
        a[4] = f2bf(a1.x); a[5] = f2bf(a1.y); a[6] = f2bf(a1.z); a[7] = f2bf(a1.w);
#pragma unroll
        for (int nt = 0; nt < 2; nt++) {
            bf16x8 b = *(const bf16x8*)(W + (size_t)(n0 + (nt << 4) + ln) * 256
                                          + (k8 << 5) + (quad << 3));
            acc[nt] = __builtin_amdgcn_mfma_f32_16x16x32_bf16(a, b, acc[nt], 0, 0, 0);
        }
    }

    const float scale = 0.17677669529663689f;  // 32^-0.5
#pragma unroll
    for (int nt = 0; nt < 2; nt++) {
        const int n = n0 + (nt << 4) + ln;
        const int h = n >> 6, c2 = n & 63;
#pragma unroll
        for (int r = 0; r < 4; r++) {
            const int m = m0 + (wq << 4) + (quad << 2) + r;
            const float v = acc[nt][r];
            if (z == 0) {
                if (c2 < 32) qs[(((h << 11) + m) << 5) + c2] = f2bf(v * scale);
                else gs[(((h << 11) + m) << 5) + (c2 - 32)] = 1.0f / (1.0f + __expf(-v));
            } else {
                if (c2 < 32) ks[(((h << 11) + m) << 5) + c2] = f2bf(v);
                else vT[(((h << 5) + (c2 - 32)) << 11) + m] = f2bf(v);
            }
        }
    }
}

// ---------------------------------------------------------------------------
// MFMA flash attention — no LDS, no barriers. Bias loaded DIRECTLY from
// global in MFMA C-layout (aligned float4, full-cache-line segments).
// S^T = K*Q^T (bias as C-init), per-lane online softmax (2 shuffles),
// PV via quad-local k-permutation. grid (32, 8, nsplit), 4 waves/block.
// ---------------------------------------------------------------------------
__global__ __launch_bounds__(256, 6)
void attn_kernel(const short* __restrict__ qs, const short* __restrict__ ks,
                 const short* __restrict__ vT, const float* __restrict__ bias,
                 float* __restrict__ Opart, float* __restrict__ mpart,
                 float* __restrict__ lpart, int ksize)
{
    const int h = blockIdx.y, z = blockIdx.z;
    const int q0 = blockIdx.x << 6;
    const int tid = threadIdx.x;
    const int wq = tid >> 6, lane = tid & 63;
    const int ln = lane & 15, quad = lane >> 4;

    const int qrow = q0 + (wq << 4) + ln;
    const bf16x8 qf = *(const bf16x8*)(qs + (((size_t)(h << 11) + qrow) << 5) + (quad << 3));

    const float L2E = 1.44269504088896f;
    float ml2 = -1e30f, l = 0.f;
    f32x4 O0 = {0, 0, 0, 0}, O1 = {0, 0, 0, 0};

    const int kbeg  = z * ksize;
    const int ntile = ksize >> 6;
    // Per-lane base pointers
    const float* bp = bias + ((size_t)h * SEQ + qrow) * SEQ + kbeg + (quad << 2);
    const short* kp = ks + (((size_t)(h << 11) + kbeg + ln) << 5) + (quad << 3);

    for (int kt = 0; kt < ntile; kt++) {
        const int k0 = kbeg + (kt << 6);

        // --- bias directly in C-layout: rows of 64B, full lines consumed ---
        f32x4 cb[4];
#pragma unroll
        for (int mt = 0; mt < 4; mt++)
            cb[mt] = *(const f32x4*)(bp + (kt << 6) + (mt << 4));
        // --- K fragments (16B contiguous per lane) ---
        bf16x8 kf[4];
#pragma unroll
        for (int mt = 0; mt < 4; mt++)
            kf[mt] = *(const bf16x8*)(kp + (size_t)(((kt << 6) + (mt << 4)) << 5));
        // --- V fragments (8B pieces from vT[h][c][s]) ---
        bf16x4 vh[2][2][2];
#pragma unroll
        for (int cm = 0; cm < 2; cm++) {
            const size_t vb = (((size_t)(h << 5) + (cm << 4) + ln) << 11) + k0 + (quad << 2);
#pragma unroll
            for (int kc = 0; kc < 2; kc++)
#pragma unroll
                for (int hf = 0; hf < 2; hf++)
                    vh[cm][kc][hf] = *(const bf16x4*)(vT + vb + (kc << 5) + (hf << 4));
        }

        // --- QK^T: S^T[k][q], bias as C ---
        f32x4 S[4];
#pragma unroll
        for (int mt = 0; mt < 4; mt++)
            S[mt] = __builtin_amdgcn_mfma_f32_16x16x32_bf16(kf[mt], qf, cb[mt], 0, 0, 0);

        // --- online softmax (per-lane q; reduce across quads) ---
        float smax = S[0][0];
#pragma unroll
        for (int mt = 0; mt < 4; mt++)
#pragma unroll
            for (int r = 0; r < 4; r++) smax = fmaxf(smax, S[mt][r]);
        smax = fmaxf(smax, __shfl_xor(smax, 16));
        smax = fmaxf(smax, __shfl_xor(smax, 32));
        const float mnew = fmaxf(ml2, smax * L2E);
        const float alpha = exp2f(ml2 - mnew);
        ml2 = mnew;

        float pr[4][4];
        float rs = 0.f;
#pragma unroll
        for (int mt = 0; mt < 4; mt++)
#pragma unroll
            for (int r = 0; r < 4; r++) {
                const float p = exp2f(fmaf(S[mt][r], L2E, -mnew));
                pr[mt][r] = p;
                rs += p;
            }
        rs += __shfl_xor(rs, 16);
        rs += __shfl_xor(rs, 32);
        l = l * alpha + rs;

        // --- pack P (quad-local k-permutation: no shuffle/LDS) ---
        short pb[4][4];
#pragma unroll
        for (int mt = 0; mt < 4; mt++)
#pragma unroll
            for (int r = 0; r < 4; r++) pb[mt][r] = f2bf(pr[mt][r]);
        bf16x8 P0 = {pb[0][0], pb[0][1], pb[0][2], pb[0][3],
                     pb[1][0], pb[1][1], pb[1][2], pb[1][3]};
        bf16x8 P1 = {pb[2][0], pb[2][1], pb[2][2], pb[2][3],
                     pb[3][0], pb[3][1], pb[3][2], pb[3][3]};

        // --- PV: O^T[c][q] accumulate ---
        O0 *= alpha;
        O1 *= alpha;
#pragma unroll
        for (int kc = 0; kc < 2; kc++) {
            const bf16x8 P = kc ? P1 : P0;
            bf16x8 va0 = __builtin_shufflevector(vh[0][kc][0], vh[0][kc][1],
                                                 0, 1, 2, 3, 4, 5, 6, 7);
            bf16x8 va1 = __builtin_shufflevector(vh[1][kc][0], vh[1][kc][1],
                                                 0, 1, 2, 3, 4, 5, 6, 7);
            O0 = __builtin_amdgcn_mfma_f32_16x16x32_bf16(va0, P, O0, 0, 0, 0);
            O1 = __builtin_amdgcn_mfma_f32_16x16x32_bf16(va1, P, O1, 0, 0, 0);
        }
    }

    // --- epilogue: unnormalized partials (mpart in log2 domain) ---
    const size_t pb_ = (((size_t)(z * NHEAD + h)) << 11) + qrow;
    if (quad == 0) { mpart[pb_] = ml2; lpart[pb_] = l; }
    float* op = Opart + (pb_ << 5);
#pragma unroll
    for (int r = 0; r < 4; r++) {
        op[(quad << 2) + r]      = O0[r];
        op[16 + (quad << 2) + r] = O1[r];
    }
}

// ---------------------------------------------------------------------------
// Combine k-split partials + 1/l + sigmoid gate -> att bf16 [s][h*32+c]
// ---------------------------------------------------------------------------
__global__ __launch_bounds__(256)
void combine_kernel(const float* __restrict__ Opart, const float* __restrict__ mpart,
                    const float* __restrict__ lpart, const float* __restrict__ gs,
                    short* __restrict__ att, int nsplit)
{
    const int g  = blockIdx.x * 256 + threadIdx.x;  // 131072
    const int c4 = g & 7;
    const int q  = (g >> 3) & (SEQ - 1);
    const int h  = g >> 14;

    float M = -1e30f;
    for (int s = 0; s < nsplit; s++)
        M = fmaxf(M, mpart[(((size_t)s * NHEAD + h) << 11) + q]);

    float l = 0.f;
    float4 O = {0.f, 0.f, 0.f, 0.f};
    for (int s = 0; s < nsplit; s++) {
        const size_t base = (((size_t)s * NHEAD + h) << 11) + q;
        const float w = exp2f(mpart[base] - M);
        l += w * lpart[base];
        float4 o4 = *(const float4*)(Opart + (base << 5) + (c4 << 2));
        O.x = fmaf(w, o4.x, O.x); O.y = fmaf(w, o4.y, O.y);
        O.z = fmaf(w, o4.z, O.z); O.w = fmaf(w, o4.w, O.w);
    }
    const float inv = 1.0f / l;
    float4 g4 = *(const float4*)(gs + ((((size_t)h << 11) + q) << 5) + (c4 << 2));
    bf16x4 r;
    r[0] = f2bf(O.x * inv * g4.x); r[1] = f2bf(O.y * inv * g4.y);
    r[2] = f2bf(O.z * inv * g4.z); r[3] = f2bf(O.w * inv * g4.w);
    *(bf16x4*)(att + ((size_t)q << 8) + (h << 5) + (c4 << 2)) = r;
}

// ---------------------------------------------------------------------------
// Output projection, MFMA: out[2048,256] = att(bf16) @ o_w + o_b.
// Wave tile 16m x 16n over K=256; 4 waves on m. grid (32,16).
// ---------------------------------------------------------------------------
__global__ __launch_bounds__(256)
void proj_o_kernel(const short* __restrict__ att, const short* __restrict__ owT,
                   const float* __restrict__ o_b, float* __restrict__ out)
{
    const int tid = threadIdx.x;
    const int wq = tid >> 6, lane = tid & 63;
    const int ln = lane & 15, quad = lane >> 4;
    const int m0 = blockIdx.x << 6;
    const int n0 = blockIdx.y << 4;

    const int n = n0 + ln;
    const float b = o_b[n];
    f32x4 acc = (f32x4){b, b, b, b};

    const short* ap = att + (size_t)(m0 + (wq << 4) + ln) * 256 + (quad << 3);
    const short* bp = owT + (size_t)n * 256 + (quad << 3);
#pragma unroll
    for (int k8 = 0; k8 < 8; k8++) {
        bf16x8 a = *(const bf16x8*)(ap + (k8 << 5));
        bf16x8 w = *(const bf16x8*)(bp + (k8 << 5));
        acc = __builtin_amdgcn_mfma_f32_16x16x32_bf16(a, w, acc, 0, 0, 0);
    }
#pragma unroll
    for (int r = 0; r < 4; r++) {
        const int m = m0 + (wq << 4) + (quad << 2) + r;
        out[(size_t)m * 256 + n] = acc[r];
    }
}

// ---------------------------------------------------------------------------
extern "C" void kernel_launch(void* const* d_in, const int* in_sizes, int n_in,
                              void* d_out, int out_size, void* d_ws, size_t ws_size,
                              hipStream_t stream)
{
    const float* q_in  = (const float*)d_in[0];
    const float* kv_in = (const float*)d_in[1];
    const float* bias  = (const float*)d_in[2];
    const float* qg_w  = (const float*)d_in[3];
    const float* kv_w  = (const float*)d_in[4];
    const float* qg_b  = (const float*)d_in[5];
    const float* kv_b  = (const float*)d_in[6];
    const float* o_w   = (const float*)d_in[7];
    const float* o_b   = (const float*)d_in[8];
    float* out = (float*)d_out;

    // Workspace layout (bytes)
    char* p = (char*)d_ws;
    short* qs   = (short*)p; p += 1048576;   // bf16 [h][s][32], pre-scaled
    short* ksb  = (short*)p; p += 1048576;   // bf16 [h][s][32]
    short* vTb  = (short*)p; p += 1048576;   // bf16 [h][c][s]
    short* attb = (short*)p; p += 1048576;   // bf16 [s][h*32+c]
    short* wqgT = (short*)p; p += 262144;    // bf16 [512][256]
    short* wkvT = (short*)p; p += 262144;    // bf16 [512][256]
    short* owT  = (short*)p; p += 131072;    // bf16 [256][256]
    float* gs   = (float*)p; p += 2097152;   // f32  [h][s][32] sigmoid(g)

    // nsplit from ws_size only (constant across calls; graph-safe)
    const size_t fixed = (size_t)(p - (char*)d_ws);
    int nsplit = 1;
    {
        const int cand[4] = {8, 4, 2, 1};
        for (int i = 0; i < 4; i++) {
            size_t ns = (size_t)cand[i];
            if (fixed + ns * (size_t)(2097152 + 2 * 65536) <= ws_size) {
                nsplit = cand[i]; break;
            }
        }
    }
    float* mp = (float*)p;                           // [ns][8][2048]
    float* lp = mp + (size_t)nsplit * NHEAD * SEQ;
    float* Op = lp + (size_t)nsplit * NHEAD * SEQ;   // [ns][8][2048][32]

    hipLaunchKernelGGL(prep_w_kernel, dim3(80), dim3(256), 0, stream,
                       qg_w, kv_w, o_w, wqgT, wkvT, owT);
    hipLaunchKernelGGL(proj_qgkv_kernel, dim3(32, 16, 2), dim3(256), 0, stream,
                       q_in, kv_in, wqgT, wkvT, qg_b, kv_b, qs, gs, ksb, vTb);
    hipLaunchKernelGGL(attn_kernel, dim3(32, NHEAD, nsplit), dim3(256), 0, stream,
                       qs, ksb, vTb, bias, Op, mp, lp, SEQ / nsplit);
    hipLaunchKernelGGL(combine_kernel, dim3(512), dim3(256), 0, stream,
                       Op, mp, lp, gs, attb, nsplit);
    hipLaunchKernelGGL(proj_o_kernel, dim3(32, 16), dim3(256), 0, stream,
                       attb, owT, o_b, out);
}

// Round 5
// 248.466 us; speedup vs baseline: 1.0606x; 1.0606x over previous
//
#include <hip/hip_runtime.h>
#include <hip/hip_bf16.h>
#include <math.h>

#define SEQ   2048
#define NHEAD 8

typedef __attribute__((ext_vector_type(8))) short bf16x8;
typedef __attribute__((ext_vector_type(4))) short bf16x4;
typedef __attribute__((ext_vector_type(4))) float f32x4;

static __device__ __forceinline__ short f2bf(float f) {
    __hip_bfloat16 h = __float2bfloat16(f);   // RNE
    return *reinterpret_cast<short*>(&h);
}

// ---------------------------------------------------------------------------
// Weight prep: LDS-tiled 64x64 transpose + bf16 cast (coalesced both sides).
// ---------------------------------------------------------------------------
__global__ __launch_bounds__(256)
void prep_w_kernel(const float* __restrict__ qg_w, const float* __restrict__ kv_w,
                   const float* __restrict__ o_w, short* __restrict__ wqgT,
                   short* __restrict__ wkvT, short* __restrict__ owT)
{
    __shared__ float t[64][65];
    int bid = blockIdx.x;
    const float* src; short* dst; int N, tr, tc;
    if (bid < 32)      { src = qg_w; dst = wqgT; N = 512; tr = bid >> 3; tc = bid & 7; }
    else if (bid < 64) { bid -= 32; src = kv_w; dst = wkvT; N = 512; tr = bid >> 3; tc = bid & 7; }
    else               { bid -= 64; src = o_w;  dst = owT;  N = 256; tr = bid >> 2; tc = bid & 3; }

    const int tid = threadIdx.x;
    const int rr = tid >> 6;       // 0..3
    const int cc = tid & 63;
#pragma unroll
    for (int s = 0; s < 16; s++)
        t[(s << 2) + rr][cc] =
            src[(size_t)((tr << 6) + (s << 2) + rr) * N + (tc << 6) + cc];
    __syncthreads();
#pragma unroll
    for (int s = 0; s < 16; s++)
        dst[(size_t)((tc << 6) + (s << 2) + rr) * 256 + (tr << 6) + cc]
            = f2bf(t[cc][(s << 2) + rr]);
}

// ---------------------------------------------------------------------------
// QG/KV projection, MFMA, explicit 2-stage K-pipeline.
// z=0: QG -> qs(bf16,*scale), gs(f32 sigmoid). z=1: KV -> ks(bf16),
// vP(bf16, PV-fragment-native layout [h][kt64][kc][quad][c][8]).
// Wave tile 16m x 32n over K=256; 4 waves on m. grid (32,16,2).
// ---------------------------------------------------------------------------
__global__ __launch_bounds__(256, 4)
void proj_qgkv_kernel(const float* __restrict__ q_in, const float* __restrict__ kv_in,
                      const short* __restrict__ wqgT, const short* __restrict__ wkvT,
                      const float* __restrict__ qg_b, const float* __restrict__ kv_b,
                      short* __restrict__ qs, float* __restrict__ gs,
                      short* __restrict__ ks, short* __restrict__ vP)
{
    const int z = blockIdx.z;
    const float* __restrict__ A  = z ? kv_in : q_in;
    const short* __restrict__ W  = z ? wkvT : wqgT;
    const float* __restrict__ bv = z ? kv_b : qg_b;

    const int tid = threadIdx.x;
    const int wq = tid >> 6, lane = tid & 63;
    const int ln = lane & 15, quad = lane >> 4;
    const int m0 = blockIdx.x << 6;
    const int n0 = blockIdx.y << 5;

    f32x4 acc[2];
#pragma unroll
    for (int nt = 0; nt < 2; nt++) {
        const float b = bv[n0 + (nt << 4) + ln];
        acc[nt] = (f32x4){b, b, b, b};
    }

    const float* ap = A + (size_t)(m0 + (wq << 4) + ln) * 256 + (quad << 3);
    const short* wp = W + (size_t)(n0 + ln) * 256 + (quad << 3);

    float4 a4[2][2]; bf16x8 wb[2][2];
    auto ldp = [&](int b, int k8) {
        a4[b][0] = *(const float4*)(ap + (k8 << 5));
        a4[b][1] = *(const float4*)(ap + (k8 << 5) + 4);
        wb[b][0] = *(const bf16x8*)(wp + (k8 << 5));
        wb[b][1] = *(const bf16x8*)(wp + 4096 + (k8 << 5));   // nt=1: +16*256
    };
    ldp(0, 0);
#pragma unroll
    for (int k8 = 0; k8 < 8; k8++) {
        const int b = k8 & 1;
        if (k8 < 7) ldp(b ^ 1, k8 + 1);
        bf16x8 a;
        a[0] = f2bf(a4[b][0].x); a[1] = f2bf(a4[b][0].y);
        a[2] = f2bf(a4[b][0].z); a[3] = f2bf(a4[b][0].w);
        a[4] = f2bf(a4[b][1].x); a[5] = f2bf(a4[b][1].y);
        a[6] = f2bf(a4[b][1].z); a[7] = f2bf(a4[b][1].w);
        acc[0] = __builtin_amdgcn_mfma_f32_16x16x32_bf16(a, wb[b][0], acc[0], 0, 0, 0);
        acc[1] = __builtin_amdgcn_mfma_f32_16x16x32_bf16(a, wb[b][1], acc[1], 0, 0, 0);
    }

    const float scale = 0.17677669529663689f;  // 32^-0.5
#pragma unroll
    for (int nt = 0; nt < 2; nt++) {
        const int n = n0 + (nt << 4) + ln;
        const int h = n >> 6, c2 = n & 63;
        if (z == 0) {
#pragma unroll
            for (int r = 0; r < 4; r++) {
                const int m = m0 + (wq << 4) + (quad << 2) + r;
                const float v = acc[nt][r];
                if (c2 < 32) qs[(((h << 11) + m) << 5) + c2] = f2bf(v * scale);
                else gs[(((h << 11) + m) << 5) + (c2 - 32)] = 1.0f / (1.0f + __expf(-v));
            }
        } else if (c2 < 32) {
#pragma unroll
            for (int r = 0; r < 4; r++) {
                const int m = m0 + (wq << 4) + (quad << 2) + r;
                ks[(((h << 11) + m) << 5) + c2] = f2bf(acc[nt][r]);
            }
        } else {
            // vP[h][kt64][kc][quad][c][8]; this thread's 4 m's are j-contiguous
            const int c  = c2 - 32;
            const int kt = m0 >> 6;            // blockIdx.x
            const int kc = wq >> 1;
            const int jb = (wq & 1) << 2;
            bf16x4 v4;
            v4[0] = f2bf(acc[nt][0]); v4[1] = f2bf(acc[nt][1]);
            v4[2] = f2bf(acc[nt][2]); v4[3] = f2bf(acc[nt][3]);
            *(bf16x4*)(vP + (size_t)((((h << 5) + kt) * 2 + kc) * 4 + quad) * 256
                          + (c << 3) + jb) = v4;
        }
    }
}

// ---------------------------------------------------------------------------
// MFMA flash attention — no LDS/barriers, explicit 2-deep register pipeline.
// Bias loaded directly in MFMA C-layout; S^T = K*Q^T; per-lane online
// softmax (2 shuffles); PV via quad-local k-permutation with V in
// fragment-native vP layout (16B loads). grid (32, 8, nsplit), 4 waves.
// ---------------------------------------------------------------------------
template<int NTILE>
__global__ __launch_bounds__(256, 3)
void attn_kernel(const short* __restrict__ qs, const short* __restrict__ ks,
                 const short* __restrict__ vP, const float* __restrict__ bias,
                 float* __restrict__ Opart, float* __restrict__ mpart,
                 float* __restrict__ lpart)
{
    const int h = blockIdx.y, z = blockIdx.z;
    const int q0 = blockIdx.x << 6;
    const int tid = threadIdx.x;
    const int wq = tid >> 6, lane = tid & 63;
    const int ln = lane & 15, quad = lane >> 4;

    const int qrow = q0 + (wq << 4) + ln;
    const bf16x8 qf = *(const bf16x8*)(qs + (((size_t)(h << 11) + qrow) << 5) + (quad << 3));

    const float L2E = 1.44269504088896f;
    float ml2 = -1e30f, l = 0.f;
    f32x4 O0 = {0, 0, 0, 0}, O1 = {0, 0, 0, 0};

    const int kbeg = z * (NTILE << 6);
    const float* bp  = bias + ((size_t)h * SEQ + qrow) * SEQ + kbeg + (quad << 2);
    const short* kp  = ks + (((size_t)(h << 11) + kbeg + ln) << 5) + (quad << 3);
    const short* vp0 = vP + (size_t)((((h << 5) + (kbeg >> 6)) * 2) * 4 + quad) * 256
                          + (ln << 3);

    f32x4 cb[2][4]; bf16x8 kf[2][4]; bf16x8 vf[2][2][2];   // [buf][cm][kc]
    auto ld = [&](int b, int t) {
#pragma unroll
        for (int mt = 0; mt < 4; mt++) {
            cb[b][mt] = *(const f32x4*)(bp + (t << 6) + (mt << 4));
            kf[b][mt] = *(const bf16x8*)(kp + ((size_t)((t << 6) + (mt << 4)) << 5));
        }
#pragma unroll
        for (int kc = 0; kc < 2; kc++)
#pragma unroll
            for (int cm = 0; cm < 2; cm++)
                vf[b][cm][kc] = *(const bf16x8*)(vp0 + (size_t)(t << 11)
                                                 + (kc << 10) + (cm << 7));
    };

    ld(0, 0);
#pragma unroll
    for (int kt = 0; kt < NTILE; kt++) {
        const int b = kt & 1;
        if (kt + 1 < NTILE) ld(b ^ 1, kt + 1);   // prefetch next tile

        // --- QK^T: S^T[k][q], bias as C ---
        f32x4 S[4];
#pragma unroll
        for (int mt = 0; mt < 4; mt++)
            S[mt] = __builtin_amdgcn_mfma_f32_16x16x32_bf16(kf[b][mt], qf,
                                                            cb[b][mt], 0, 0, 0);

        // --- online softmax (per-lane q; reduce across quads) ---
        float smax = S[0][0];
#pragma unroll
        for (int mt = 0; mt < 4; mt++)
#pragma unroll
            for (int r = 0; r < 4; r++) smax = fmaxf(smax, S[mt][r]);
        smax = fmaxf(smax, __shfl_xor(smax, 16));
        smax = fmaxf(smax, __shfl_xor(smax, 32));
        const float mnew = fmaxf(ml2, smax * L2E);
        const float alpha = exp2f(ml2 - mnew);
        ml2 = mnew;

        float pr[4][4];
        float rs = 0.f;
#pragma unroll
        for (int mt = 0; mt < 4; mt++)
#pragma unroll
            for (int r = 0; r < 4; r++) {
                const float p = exp2f(fmaf(S[mt][r], L2E, -mnew));
                pr[mt][r] = p;
                rs += p;
            }
        rs += __shfl_xor(rs, 16);
        rs += __shfl_xor(rs, 32);
        l = l * alpha + rs;

        // --- pack P (quad-local k-permutation) ---
        short pb[4][4];
#pragma unroll
        for (int mt = 0; mt < 4; mt++)
#pragma unroll
            for (int r = 0; r < 4; r++) pb[mt][r] = f2bf(pr[mt][r]);
        bf16x8 P0 = {pb[0][0], pb[0][1], pb[0][2], pb[0][3],
                     pb[1][0], pb[1][1], pb[1][2], pb[1][3]};
        bf16x8 P1 = {pb[2][0], pb[2][1], pb[2][2], pb[2][3],
                     pb[3][0], pb[3][1], pb[3][2], pb[3][3]};

        // --- PV: O^T[c][q] accumulate ---
        O0 *= alpha;
        O1 *= alpha;
        O0 = __builtin_amdgcn_mfma_f32_16x16x32_bf16(vf[b][0][0], P0, O0, 0, 0, 0);
        O1 = __builtin_amdgcn_mfma_f32_16x16x32_bf16(vf[b][1][0], P0, O1, 0, 0, 0);
        O0 = __builtin_amdgcn_mfma_f32_16x16x32_bf16(vf[b][0][1], P1, O0, 0, 0, 0);
        O1 = __builtin_amdgcn_mfma_f32_16x16x32_bf16(vf[b][1][1], P1, O1, 0, 0, 0);
    }

    // --- epilogue: unnormalized partials (mpart in log2 domain) ---
    const size_t pb_ = (((size_t)(z * NHEAD + h)) << 11) + qrow;
    if (quad == 0) { mpart[pb_] = ml2; lpart[pb_] = l; }
    float* op = Opart + (pb_ << 5);
    *(f32x4*)(op + (quad << 2))      = O0;
    *(f32x4*)(op + 16 + (quad << 2)) = O1;
}

// ---------------------------------------------------------------------------
// Combine k-split partials + 1/l + sigmoid gate -> att bf16 [s][h*32+c]
// ---------------------------------------------------------------------------
__global__ __launch_bounds__(256)
void combine_kernel(const float* __restrict__ Opart, const float* __restrict__ mpart,
                    const float* __restrict__ lpart, const float* __restrict__ gs,
                    short* __restrict__ att, int nsplit)
{
    const int g  = blockIdx.x * 256 + threadIdx.x;  // 131072
    const int c4 = g & 7;
    const int q  = (g >> 3) & (SEQ - 1);
    const int h  = g >> 14;

    float M = -1e30f;
    for (int s = 0; s < nsplit; s++)
        M = fmaxf(M, mpart[(((size_t)s * NHEAD + h) << 11) + q]);

    float l = 0.f;
    float4 O = {0.f, 0.f, 0.f, 0.f};
    for (int s = 0; s < nsplit; s++) {
        const size_t base = (((size_t)s * NHEAD + h) << 11) + q;
        const float w = exp2f(mpart[base] - M);
        l += w * lpart[base];
        float4 o4 = *(const float4*)(Opart + (base << 5) + (c4 << 2));
        O.x = fmaf(w, o4.x, O.x); O.y = fmaf(w, o4.y, O.y);
        O.z = fmaf(w, o4.z, O.z); O.w = fmaf(w, o4.w, O.w);
    }
    const float inv = 1.0f / l;
    float4 g4 = *(const float4*)(gs + ((((size_t)h << 11) + q) << 5) + (c4 << 2));
    bf16x4 r;
    r[0] = f2bf(O.x * inv * g4.x); r[1] = f2bf(O.y * inv * g4.y);
    r[2] = f2bf(O.z * inv * g4.z); r[3] = f2bf(O.w * inv * g4.w);
    *(bf16x4*)(att + ((size_t)q << 8) + (h << 5) + (c4 << 2)) = r;
}

// ---------------------------------------------------------------------------
// Output projection, MFMA: out[2048,256] = att(bf16) @ o_w + o_b.
// ---------------------------------------------------------------------------
__global__ __launch_bounds__(256, 4)
void proj_o_kernel(const short* __restrict__ att, const short* __restrict__ owT,
                   const float* __restrict__ o_b, float* __restrict__ out)
{
    const int tid = threadIdx.x;
    const int wq = tid >> 6, lane = tid & 63;
    const int ln = lane & 15, quad = lane >> 4;
    const int m0 = blockIdx.x << 6;
    const int n0 = blockIdx.y << 4;

    const int n = n0 + ln;
    const float b = o_b[n];
    f32x4 acc = (f32x4){b, b, b, b};

    const short* ap = att + (size_t)(m0 + (wq << 4) + ln) * 256 + (quad << 3);
    const short* bp = owT + (size_t)n * 256 + (quad << 3);

    bf16x8 a2[2], w2[2];
    a2[0] = *(const bf16x8*)(ap);  w2[0] = *(const bf16x8*)(bp);
#pragma unroll
    for (int k8 = 0; k8 < 8; k8++) {
        const int b_ = k8 & 1;
        if (k8 < 7) {
            a2[b_ ^ 1] = *(const bf16x8*)(ap + ((k8 + 1) << 5));
            w2[b_ ^ 1] = *(const bf16x8*)(bp + ((k8 + 1) << 5));
        }
        acc = __builtin_amdgcn_mfma_f32_16x16x32_bf16(a2[b_], w2[b_], acc, 0, 0, 0);
    }
#pragma unroll
    for (int r = 0; r < 4; r++) {
        const int m = m0 + (wq << 4) + (quad << 2) + r;
        out[(size_t)m * 256 + n] = acc[r];
    }
}

// ---------------------------------------------------------------------------
extern "C" void kernel_launch(void* const* d_in, const int* in_sizes, int n_in,
                              void* d_out, int out_size, void* d_ws, size_t ws_size,
                              hipStream_t stream)
{
    const float* q_in  = (const float*)d_in[0];
    const float* kv_in = (const float*)d_in[1];
    const float* bias  = (const float*)d_in[2];
    const float* qg_w  = (const float*)d_in[3];
    const float* kv_w  = (const float*)d_in[4];
    const float* qg_b  = (const float*)d_in[5];
    const float* kv_b  = (const float*)d_in[6];
    const float* o_w   = (const float*)d_in[7];
    const float* o_b   = (const float*)d_in[8];
    float* out = (float*)d_out;

    // Workspace layout (bytes)
    char* p = (char*)d_ws;
    short* qs   = (short*)p; p += 1048576;   // bf16 [h][s][32], pre-scaled
    short* ksb  = (short*)p; p += 1048576;   // bf16 [h][s][32]
    short* vPb  = (short*)p; p += 1048576;   // bf16 [h][kt][kc][quad][c][8]
    short* attb = (short*)p; p += 1048576;   // bf16 [s][h*32+c]
    short* wqgT = (short*)p; p += 262144;    // bf16 [512][256]
    short* wkvT = (short*)p; p += 262144;    // bf16 [512][256]
    short* owT  = (short*)p; p += 131072;    // bf16 [256][256]
    float* gs   = (float*)p; p += 2097152;   // f32  [h][s][32] sigmoid(g)

    // nsplit from ws_size only (constant across calls; graph-safe)
    const size_t fixed = (size_t)(p - (char*)d_ws);
    int nsplit = 1;
    {
        const int cand[4] = {8, 4, 2, 1};
        for (int i = 0; i < 4; i++) {
            size_t ns = (size_t)cand[i];
            if (fixed + ns * (size_t)(2097152 + 2 * 65536) <= ws_size) {
                nsplit = cand[i]; break;
            }
        }
    }
    float* mp = (float*)p;                           // [ns][8][2048]
    float* lp = mp + (size_t)nsplit * NHEAD * SEQ;
    float* Op = lp + (size_t)nsplit * NHEAD * SEQ;   // [ns][8][2048][32]

    hipLaunchKernelGGL(prep_w_kernel, dim3(80), dim3(256), 0, stream,
                       qg_w, kv_w, o_w, wqgT, wkvT, owT);
    hipLaunchKernelGGL(proj_qgkv_kernel, dim3(32, 16, 2), dim3(256), 0, stream,
                       q_in, kv_in, wqgT, wkvT, qg_b, kv_b, qs, gs, ksb, vPb);
    switch (nsplit) {
    case 8:
        hipLaunchKernelGGL((attn_kernel<4>), dim3(32, NHEAD, 8), dim3(256), 0, stream,
                           qs, ksb, vPb, bias, Op, mp, lp); break;
    case 4:
        hipLaunchKernelGGL((attn_kernel<8>), dim3(32, NHEAD, 4), dim3(256), 0, stream,
                           qs, ksb, vPb, bias, Op, mp, lp); break;
    case 2:
        hipLaunchKernelGGL((attn_kernel<16>), dim3(32, NHEAD, 2), dim3(256), 0, stream,
                           qs, ksb, vPb, bias, Op, mp, lp); break;
    default:
        hipLaunchKernelGGL((attn_kernel<32>), dim3(32, NHEAD, 1), dim3(256), 0, stream,
                           qs, ksb, vPb, bias, Op, mp, lp); break;
    }
    hipLaunchKernelGGL(combine_kernel, dim3(512), dim3(256), 0, stream,
                       Op, mp, lp, gs, attb, nsplit);
    hipLaunchKernelGGL(proj_o_kernel, dim3(32, 16), dim3(256), 0, stream,
                       attb, owT, o_b, out);
}

// Round 6
// 241.847 us; speedup vs baseline: 1.0896x; 1.0274x over previous
//
#include <hip/hip_runtime.h>
#include <hip/hip_bf16.h>
#include <math.h>

#define SEQ   2048
#define NHEAD 8

typedef __attribute__((ext_vector_type(8))) short bf16x8;
typedef __attribute__((ext_vector_type(4))) short bf16x4;
typedef __attribute__((ext_vector_type(4))) float f32x4;

static __device__ __forceinline__ short f2bf(float f) {
    __hip_bfloat16 h = __float2bfloat16(f);   // RNE
    return *reinterpret_cast<short*>(&h);
}

// ---------------------------------------------------------------------------
// Weight prep: LDS-tiled 64x64 transpose + bf16 cast (coalesced both sides).
// ---------------------------------------------------------------------------
__global__ __launch_bounds__(256)
void prep_w_kernel(const float* __restrict__ qg_w, const float* __restrict__ kv_w,
                   const float* __restrict__ o_w, short* __restrict__ wqgT,
                   short* __restrict__ wkvT, short* __restrict__ owT)
{
    __shared__ float t[64][65];
    int bid = blockIdx.x;
    const float* src; short* dst; int N, tr, tc;
    if (bid < 32)      { src = qg_w; dst = wqgT; N = 512; tr = bid >> 3; tc = bid & 7; }
    else if (bid < 64) { bid -= 32; src = kv_w; dst = wkvT; N = 512; tr = bid >> 3; tc = bid & 7; }
    else               { bid -= 64; src = o_w;  dst = owT;  N = 256; tr = bid >> 2; tc = bid & 3; }

    const int tid = threadIdx.x;
    const int rr = tid >> 6;       // 0..3
    const int cc = tid & 63;
#pragma unroll
    for (int s = 0; s < 16; s++)
        t[(s << 2) + rr][cc] =
            src[(size_t)((tr << 6) + (s << 2) + rr) * N + (tc << 6) + cc];
    __syncthreads();
#pragma unroll
    for (int s = 0; s < 16; s++)
        dst[(size_t)((tc << 6) + (s << 2) + rr) * 256 + (tr << 6) + cc]
            = f2bf(t[cc][(s << 2) + rr]);
}

// ---------------------------------------------------------------------------
// QG/KV projection, MFMA, explicit 2-stage K-pipeline.
// z=0: QG -> qs(bf16,*scale), gs(f32 sigmoid). z=1: KV -> ks(bf16),
// vP(bf16, PV-fragment-native layout [h][kt64][kc][quad][c][8]).
// Wave tile 16m x 32n over K=256; 4 waves on m. grid (32,16,2).
// ---------------------------------------------------------------------------
__global__ __launch_bounds__(256, 4)
void proj_qgkv_kernel(const float* __restrict__ q_in, const float* __restrict__ kv_in,
                      const short* __restrict__ wqgT, const short* __restrict__ wkvT,
                      const float* __restrict__ qg_b, const float* __restrict__ kv_b,
                      short* __restrict__ qs, float* __restrict__ gs,
                      short* __restrict__ ks, short* __restrict__ vP)
{
    const int z = blockIdx.z;
    const float* __restrict__ A  = z ? kv_in : q_in;
    const short* __restrict__ W  = z ? wkvT : wqgT;
    const float* __restrict__ bv = z ? kv_b : qg_b;

    const int tid = threadIdx.x;
    const int wq = tid >> 6, lane = tid & 63;
    const int ln = lane & 15, quad = lane >> 4;
    const int m0 = blockIdx.x << 6;
    const int n0 = blockIdx.y << 5;

    f32x4 acc[2];
#pragma unroll
    for (int nt = 0; nt < 2; nt++) {
        const float b = bv[n0 + (nt << 4) + ln];
        acc[nt] = (f32x4){b, b, b, b};
    }

    const float* ap = A + (size_t)(m0 + (wq << 4) + ln) * 256 + (quad << 3);
    const short* wp = W + (size_t)(n0 + ln) * 256 + (quad << 3);

    float4 a4[2][2]; bf16x8 wb[2][2];
    auto ldp = [&](int b, int k8) {
        a4[b][0] = *(const float4*)(ap + (k8 << 5));
        a4[b][1] = *(const float4*)(ap + (k8 << 5) + 4);
        wb[b][0] = *(const bf16x8*)(wp + (k8 << 5));
        wb[b][1] = *(const bf16x8*)(wp + 4096 + (k8 << 5));   // nt=1: +16*256
    };
    ldp(0, 0);
#pragma unroll
    for (int k8 = 0; k8 < 8; k8++) {
        const int b = k8 & 1;
        if (k8 < 7) ldp(b ^ 1, k8 + 1);
        bf16x8 a;
        a[0] = f2bf(a4[b][0].x); a[1] = f2bf(a4[b][0].y);
        a[2] = f2bf(a4[b][0].z); a[3] = f2bf(a4[b][0].w);
        a[4] = f2bf(a4[b][1].x); a[5] = f2bf(a4[b][1].y);
        a[6] = f2bf(a4[b][1].z); a[7] = f2bf(a4[b][1].w);
        acc[0] = __builtin_amdgcn_mfma_f32_16x16x32_bf16(a, wb[b][0], acc[0], 0, 0, 0);
        acc[1] = __builtin_amdgcn_mfma_f32_16x16x32_bf16(a, wb[b][1], acc[1], 0, 0, 0);
    }

    const float scale = 0.17677669529663689f;  // 32^-0.5
#pragma unroll
    for (int nt = 0; nt < 2; nt++) {
        const int n = n0 + (nt << 4) + ln;
        const int h = n >> 6, c2 = n & 63;
        if (z == 0) {
#pragma unroll
            for (int r = 0; r < 4; r++) {
                const int m = m0 + (wq << 4) + (quad << 2) + r;
                const float v = acc[nt][r];
                if (c2 < 32) qs[(((h << 11) + m) << 5) + c2] = f2bf(v * scale);
                else gs[(((h << 11) + m) << 5) + (c2 - 32)] = 1.0f / (1.0f + __expf(-v));
            }
        } else if (c2 < 32) {
#pragma unroll
            for (int r = 0; r < 4; r++) {
                const int m = m0 + (wq << 4) + (quad << 2) + r;
                ks[(((h << 11) + m) << 5) + c2] = f2bf(acc[nt][r]);
            }
        } else {
            // vP[h][kt64][kc][quad][c][8]; this thread's 4 m's are j-contiguous
            const int c  = c2 - 32;
            const int kt = m0 >> 6;            // blockIdx.x
            const int kc = wq >> 1;
            const int jb = (wq & 1) << 2;
            bf16x4 v4;
            v4[0] = f2bf(acc[nt][0]); v4[1] = f2bf(acc[nt][1]);
            v4[2] = f2bf(acc[nt][2]); v4[3] = f2bf(acc[nt][3]);
            *(bf16x4*)(vP + (size_t)((((h << 5) + kt) * 2 + kc) * 4 + quad) * 256
                          + (c << 3) + jb) = v4;
        }
    }
}

// ---------------------------------------------------------------------------
// MFMA flash attention — no LDS/barriers. 2-deep register pipeline on the
// HBM streams (bias in C-layout + K); V (L2-resident) loaded just-in-time
// BEFORE the prefetch so its waitcnt never drains the pipeline.
// S^T = K*Q^T; per-lane online softmax (2 shuffles); PV via quad-local
// k-permutation with fragment-native vP. grid (32, 8, nsplit), 4 waves.
// ---------------------------------------------------------------------------
template<int NTILE>
__global__ __launch_bounds__(256, 4)
void attn_kernel(const short* __restrict__ qs, const short* __restrict__ ks,
                 const short* __restrict__ vP, const float* __restrict__ bias,
                 float* __restrict__ Opart, float* __restrict__ mpart,
                 float* __restrict__ lpart)
{
    const int h = blockIdx.y, z = blockIdx.z;
    const int q0 = blockIdx.x << 6;
    const int tid = threadIdx.x;
    const int wq = tid >> 6, lane = tid & 63;
    const int ln = lane & 15, quad = lane >> 4;

    const int qrow = q0 + (wq << 4) + ln;
    const bf16x8 qf = *(const bf16x8*)(qs + (((size_t)(h << 11) + qrow) << 5) + (quad << 3));

    const float L2E = 1.44269504088896f;
    float ml2 = -1e30f, l = 0.f;
    f32x4 O0 = {0, 0, 0, 0}, O1 = {0, 0, 0, 0};

    const int kbeg = z * (NTILE << 6);
    const float* bp  = bias + ((size_t)h * SEQ + qrow) * SEQ + kbeg + (quad << 2);
    const short* kp  = ks + (((size_t)(h << 11) + kbeg + ln) << 5) + (quad << 3);
    const short* vp0 = vP + (size_t)((((h << 5) + (kbeg >> 6)) * 2) * 4 + quad) * 256
                          + (ln << 3);

    f32x4 cb[2][4]; bf16x8 kf[2][4];
    auto ld_cbkf = [&](int b, int t) {
#pragma unroll
        for (int mt = 0; mt < 4; mt++) {
            cb[b][mt] = *(const f32x4*)(bp + (t << 6) + (mt << 4));
            kf[b][mt] = *(const bf16x8*)(kp + ((size_t)((t << 6) + (mt << 4)) << 5));
        }
    };

    ld_cbkf(0, 0);
#pragma unroll
    for (int kt = 0; kt < NTILE; kt++) {
        const int b = kt & 1;

        // --- V for THIS tile, issued before the prefetch (older in queue) ---
        bf16x8 vf[2][2];   // [cm][kc]
#pragma unroll
        for (int kc = 0; kc < 2; kc++)
#pragma unroll
            for (int cm = 0; cm < 2; cm++)
                vf[cm][kc] = *(const bf16x8*)(vp0 + (size_t)(kt << 11)
                                              + (kc << 10) + (cm << 7));
        // --- prefetch next tile's bias+K (stays in flight through compute) ---
        if (kt + 1 < NTILE) ld_cbkf(b ^ 1, kt + 1);

        // --- QK^T: S^T[k][q], bias as C ---
        f32x4 S[4];
#pragma unroll
        for (int mt = 0; mt < 4; mt++)
            S[mt] = __builtin_amdgcn_mfma_f32_16x16x32_bf16(kf[b][mt], qf,
                                                            cb[b][mt], 0, 0, 0);

        // --- online softmax (per-lane q; reduce across quads) ---
        float smax = S[0][0];
#pragma unroll
        for (int mt = 0; mt < 4; mt++)
#pragma unroll
            for (int r = 0; r < 4; r++) smax = fmaxf(smax, S[mt][r]);
        smax = fmaxf(smax, __shfl_xor(smax, 16));
        smax = fmaxf(smax, __shfl_xor(smax, 32));
        const float mnew = fmaxf(ml2, smax * L2E);
        const float alpha = exp2f(ml2 - mnew);
        ml2 = mnew;

        float rs = 0.f;
#pragma unroll
        for (int mt = 0; mt < 4; mt++)
#pragma unroll
            for (int r = 0; r < 4; r++) {
                const float p = exp2f(fmaf(S[mt][r], L2E, -mnew));
                S[mt][r] = p;            // in-place: frees registers
                rs += p;
            }
        rs += __shfl_xor(rs, 16);
        rs += __shfl_xor(rs, 32);
        l = l * alpha + rs;

        // --- pack P (quad-local k-permutation) ---
        bf16x8 P0, P1;
#pragma unroll
        for (int r = 0; r < 4; r++) {
            P0[r]     = f2bf(S[0][r]);
            P0[4 + r] = f2bf(S[1][r]);
            P1[r]     = f2bf(S[2][r]);
            P1[4 + r] = f2bf(S[3][r]);
        }

        // --- PV: O^T[c][q] accumulate ---
        O0 *= alpha;
        O1 *= alpha;
        O0 = __builtin_amdgcn_mfma_f32_16x16x32_bf16(vf[0][0], P0, O0, 0, 0, 0);
        O1 = __builtin_amdgcn_mfma_f32_16x16x32_bf16(vf[1][0], P0, O1, 0, 0, 0);
        O0 = __builtin_amdgcn_mfma_f32_16x16x32_bf16(vf[0][1], P1, O0, 0, 0, 0);
        O1 = __builtin_amdgcn_mfma_f32_16x16x32_bf16(vf[1][1], P1, O1, 0, 0, 0);
    }

    // --- epilogue: unnormalized partials (mpart in log2 domain) ---
    const size_t pb_ = (((size_t)(z * NHEAD + h)) << 11) + qrow;
    if (quad == 0) { mpart[pb_] = ml2; lpart[pb_] = l; }
    float* op = Opart + (pb_ << 5);
    *(f32x4*)(op + (quad << 2))      = O0;
    *(f32x4*)(op + 16 + (quad << 2)) = O1;
}

// ---------------------------------------------------------------------------
// Combine k-split partials + 1/l + sigmoid gate -> att bf16 [s][h*32+c]
// ---------------------------------------------------------------------------
__global__ __launch_bounds__(256)
void combine_kernel(const float* __restrict__ Opart, const float* __restrict__ mpart,
                    const float* __restrict__ lpart, const float* __restrict__ gs,
                    short* __restrict__ att, int nsplit)
{
    const int g  = blockIdx.x * 256 + threadIdx.x;  // 131072
    const int c4 = g & 7;
    const int q  = (g >> 3) & (SEQ - 1);
    const int h  = g >> 14;

    float M = -1e30f;
    for (int s = 0; s < nsplit; s++)
        M = fmaxf(M, mpart[(((size_t)s * NHEAD + h) << 11) + q]);

    float l = 0.f;
    float4 O = {0.f, 0.f, 0.f, 0.f};
    for (int s = 0; s < nsplit; s++) {
        const size_t base = (((size_t)s * NHEAD + h) << 11) + q;
        const float w = exp2f(mpart[base] - M);
        l += w * lpart[base];
        float4 o4 = *(const float4*)(Opart + (base << 5) + (c4 << 2));
        O.x = fmaf(w, o4.x, O.x); O.y = fmaf(w, o4.y, O.y);
        O.z = fmaf(w, o4.z, O.z); O.w = fmaf(w, o4.w, O.w);
    }
    const float inv = 1.0f / l;
    float4 g4 = *(const float4*)(gs + ((((size_t)h << 11) + q) << 5) + (c4 << 2));
    bf16x4 r;
    r[0] = f2bf(O.x * inv * g4.x); r[1] = f2bf(O.y * inv * g4.y);
    r[2] = f2bf(O.z * inv * g4.z); r[3] = f2bf(O.w * inv * g4.w);
    *(bf16x4*)(att + ((size_t)q << 8) + (h << 5) + (c4 << 2)) = r;
}

// ---------------------------------------------------------------------------
// Output projection, MFMA: out[2048,256] = att(bf16) @ o_w + o_b.
// ---------------------------------------------------------------------------
__global__ __launch_bounds__(256, 4)
void proj_o_kernel(const short* __restrict__ att, const short* __restrict__ owT,
                   const float* __restrict__ o_b, float* __restrict__ out)
{
    const int tid = threadIdx.x;
    const int wq = tid >> 6, lane = tid & 63;
    const int ln = lane & 15, quad = lane >> 4;
    const int m0 = blockIdx.x << 6;
    const int n0 = blockIdx.y << 4;

    const int n = n0 + ln;
    const float b = o_b[n];
    f32x4 acc = (f32x4){b, b, b, b};

    const short* ap = att + (size_t)(m0 + (wq << 4) + ln) * 256 + (quad << 3);
    const short* bp = owT + (size_t)n * 256 + (quad << 3);

    bf16x8 a2[2], w2[2];
    a2[0] = *(const bf16x8*)(ap);  w2[0] = *(const bf16x8*)(bp);
#pragma unroll
    for (int k8 = 0; k8 < 8; k8++) {
        const int b_ = k8 & 1;
        if (k8 < 7) {
            a2[b_ ^ 1] = *(const bf16x8*)(ap + ((k8 + 1) << 5));
            w2[b_ ^ 1] = *(const bf16x8*)(bp + ((k8 + 1) << 5));
        }
        acc = __builtin_amdgcn_mfma_f32_16x16x32_bf16(a2[b_], w2[b_], acc, 0, 0, 0);
    }
#pragma unroll
    for (int r = 0; r < 4; r++) {
        const int m = m0 + (wq << 4) + (quad << 2) + r;
        out[(size_t)m * 256 + n] = acc[r];
    }
}

// ---------------------------------------------------------------------------
extern "C" void kernel_launch(void* const* d_in, const int* in_sizes, int n_in,
                              void* d_out, int out_size, void* d_ws, size_t ws_size,
                              hipStream_t stream)
{
    const float* q_in  = (const float*)d_in[0];
    const float* kv_in = (const float*)d_in[1];
    const float* bias  = (const float*)d_in[2];
    const float* qg_w  = (const float*)d_in[3];
    const float* kv_w  = (const float*)d_in[4];
    const float* qg_b  = (const float*)d_in[5];
    const float* kv_b  = (const float*)d_in[6];
    const float* o_w   = (const float*)d_in[7];
    const float* o_b   = (const float*)d_in[8];
    float* out = (float*)d_out;

    // Workspace layout (bytes)
    char* p = (char*)d_ws;
    short* qs   = (short*)p; p += 1048576;   // bf16 [h][s][32], pre-scaled
    short* ksb  = (short*)p; p += 1048576;   // bf16 [h][s][32]
    short* vPb  = (short*)p; p += 1048576;   // bf16 [h][kt][kc][quad][c][8]
    short* attb = (short*)p; p += 1048576;   // bf16 [s][h*32+c]
    short* wqgT = (short*)p; p += 262144;    // bf16 [512][256]
    short* wkvT = (short*)p; p += 262144;    // bf16 [512][256]
    short* owT  = (short*)p; p += 131072;    // bf16 [256][256]
    float* gs   = (float*)p; p += 2097152;   // f32  [h][s][32] sigmoid(g)

    // nsplit from ws_size only (constant across calls; graph-safe).
    // 4 preferred: grid = 1024 = exactly 4 blocks/CU; partial traffic 8.4 MB.
    const size_t fixed = (size_t)(p - (char*)d_ws);
    int nsplit = 1;
    {
        const int cand[3] = {4, 2, 1};
        for (int i = 0; i < 3; i++) {
            size_t ns = (size_t)cand[i];
            if (fixed + ns * (size_t)(2097152 + 2 * 65536) <= ws_size) {
                nsplit = cand[i]; break;
            }
        }
    }
    float* mp = (float*)p;                           // [ns][8][2048]
    float* lp = mp + (size_t)nsplit * NHEAD * SEQ;
    float* Op = lp + (size_t)nsplit * NHEAD * SEQ;   // [ns][8][2048][32]

    hipLaunchKernelGGL(prep_w_kernel, dim3(80), dim3(256), 0, stream,
                       qg_w, kv_w, o_w, wqgT, wkvT, owT);
    hipLaunchKernelGGL(proj_qgkv_kernel, dim3(32, 16, 2), dim3(256), 0, stream,
                       q_in, kv_in, wqgT, wkvT, qg_b, kv_b, qs, gs, ksb, vPb);
    switch (nsplit) {
    case 4:
        hipLaunchKernelGGL((attn_kernel<8>), dim3(32, NHEAD, 4), dim3(256), 0, stream,
                           qs, ksb, vPb, bias, Op, mp, lp); break;
    case 2:
        hipLaunchKernelGGL((attn_kernel<16>), dim3(32, NHEAD, 2), dim3(256), 0, stream,
                           qs, ksb, vPb, bias, Op, mp, lp); break;
    default:
        hipLaunchKernelGGL((attn_kernel<32>), dim3(32, NHEAD, 1), dim3(256), 0, stream,
                           qs, ksb, vPb, bias, Op, mp, lp); break;
    }
    hipLaunchKernelGGL(combine_kernel, dim3(512), dim3(256), 0, stream,
                       Op, mp, lp, gs, attb, nsplit);
    hipLaunchKernelGGL(proj_o_kernel, dim3(32, 16), dim3(256), 0, stream,
                       attb, owT, o_b, out);
}